// Round 19
// baseline (443.815 us; speedup 1.0000x reference)
//
#include <hip/hip_runtime.h>
#include <hip/hip_cooperative_groups.h>
#include <math.h>

namespace cg = cooperative_groups;

#define B_    2
#define TU_   1024
#define D_    80
#define H_    8
#define DH_   10
#define FFN_  2048
#define SEG_  32
#define RC_   8
#define LC_   50
#define NSEG_ 32
#define RCT_  256
#define L_    1280
#define NLAYERS_ 4
#define OUTD_ 768
#define EPS_  1e-5f
#define SCALE_ 0.31622776601683794f
#define NR_   (B_*L_)                 // 2560
#define KP_   96                      // K pad 80->96

typedef __attribute__((ext_vector_type(8))) short bf16x8;
typedef __attribute__((ext_vector_type(4))) float f32x4;
typedef unsigned short ushort_t;
typedef unsigned char uchar_t;
typedef long i64_t;

__device__ inline ushort_t f2bf(float f) {
  union { float f; unsigned u; } x; x.f = f;
  unsigned r = x.u + 0x7fffu + ((x.u >> 16) & 1u);   // RNE
  return (ushort_t)(r >> 16);
}
__device__ inline float bf2f(ushort_t u) {
  union { unsigned u; float f; } x; x.u = ((unsigned)u) << 16; return x.f;
}
__device__ inline uchar_t f2fp8(float f) {
  return (uchar_t)(__builtin_amdgcn_cvt_pk_fp8_f32(f, f, 0, false) & 0xff);
}
__device__ inline unsigned pk4fp8(float f0, float f1, float f2, float f3) {
  unsigned w = (unsigned)__builtin_amdgcn_cvt_pk_fp8_f32(f0, f1, 0, false);
  w = (unsigned)__builtin_amdgcn_cvt_pk_fp8_f32(f2, f3, (int)w, true);
  return w;
}

// ---- fragment-tiled sizes (tile = 512 elements = 64 lanes x 8) ----
#define S1_  (NLAYERS_*FFN_*KP_)       // w18 fp8 tiled [l][128 ntile][3 ktile][512]
#define S2_  (NLAYERS_*D_*FFN_)        // w28 fp8 tiled [l][5 ntile][64 ktile][512]
#define S3_  (NLAYERS_*45*512)         // wqkvT bf16 tiled [l][15][3][512]
#define S4_  (NLAYERS_*15*512)         // woT bf16 tiled [l][5][3][512]
#define S5_  (144*512)                 // pwT bf16 tiled [48][3][512]
#define S6_  (NLAYERS_*240)            // bqkv fp32
#define WSM_N_ (S3_+S4_+S5_+S6_)
#define WSM_BLK_ ((WSM_N_ + 255)/256)          // 772
#define W1_BLK_  (32*NLAYERS_)                 // 128
#define W2_BLK_  (32*NLAYERS_)                 // 128

// ============ unified weight prep (+ lengths tail) ============
__global__ __launch_bounds__(256) void k_wprep_all(
    const float* __restrict__ wq, const float* __restrict__ wkv,
    const float* __restrict__ wo, const float* __restrict__ pw,
    const float* __restrict__ bq, const float* __restrict__ bkv,
    const float* __restrict__ w1, const float* __restrict__ w2,
    ushort_t* __restrict__ wqkvT, ushort_t* __restrict__ woT,
    ushort_t* __restrict__ pwT, float* __restrict__ bqkv,
    uchar_t* __restrict__ w18, uchar_t* __restrict__ w28,
    const int* __restrict__ len, float* __restrict__ out) {
  int bx = blockIdx.x;
  int tid = threadIdx.x;
  __shared__ float t[5120];

  if (bx == 0 && tid < B_)
    out[(size_t)B_*TU_*OUTD_ + tid] = (float)len[tid];

  if (bx < WSM_BLK_) {
    int idx = bx * 256 + tid;
    if (idx < S3_) {
      int l = idx / (45*512); int rem = idx % (45*512);
      int tile = rem / 512, off = rem % 512;
      int tt = tile / 3, kt = tile % 3;
      int lane = off >> 3, j = off & 7;
      int n = tt*16 + (lane & 15);
      int k = kt*32 + (lane >> 4)*8 + j;
      float v = 0.f;
      if (k < D_) {
        if (n < D_)       v = wq[(l*D_ + k)*D_ + n] * SCALE_;
        else if (n < 240) v = wkv[(l*D_ + k)*2*D_ + (n - D_)];
      }
      wqkvT[idx] = f2bf(v);
      return;
    }
    idx -= S3_;
    if (idx < S4_) {
      int l = idx / (15*512); int rem = idx % (15*512);
      int tile = rem / 512, off = rem % 512;
      int nf = tile / 3, kt = tile % 3;
      int lane = off >> 3, j = off & 7;
      int n = nf*16 + (lane & 15);
      int k = kt*32 + (lane >> 4)*8 + j;
      woT[idx] = (k < D_) ? f2bf(wo[(l*D_ + k)*D_ + n]) : 0;
      return;
    }
    idx -= S4_;
    if (idx < S5_) {
      int tile = idx / 512, off = idx % 512;
      int tt = tile / 3, kt = tile % 3;
      int lane = off >> 3, j = off & 7;
      int n = tt*16 + (lane & 15);
      int k = kt*32 + (lane >> 4)*8 + j;
      pwT[idx] = (k < D_) ? f2bf(pw[k*OUTD_ + n]) : 0;
      return;
    }
    idx -= S5_;
    if (idx < S6_) {
      int c = idx % 240, l = idx / 240;
      bqkv[idx] = (c < D_) ? bq[l*D_ + c] * SCALE_ : bkv[l*2*D_ + (c - D_)];
    }
    return;
  }
  bx -= WSM_BLK_;
  if (bx < W1_BLK_) {
    int n0 = (bx & 31) * 64, l = bx >> 5;
    for (int idx = tid; idx < D_*64; idx += 256) {
      int k = idx >> 6, n = idx & 63;
      t[k*64 + n] = w1[((size_t)(l*D_ + k))*FFN_ + n0 + n];
    }
    __syncthreads();
    for (int idx = tid; idx < 4*3*64; idx += 256) {
      int nis = idx / 192, rem = idx % 192;
      int kt = rem / 64, lane = rem % 64;
      int r = lane & 15, g = lane >> 4;
      int nl = nis*16 + r;
      int kb = kt*32 + g*8;
      float v[8];
      #pragma unroll
      for (int j = 0; j < 8; ++j) {
        int k = kb + j;
        v[j] = (k < D_) ? t[k*64 + nl]*16.f : 0.f;
      }
      uint2 o;
      o.x = pk4fp8(v[0], v[1], v[2], v[3]);
      o.y = pk4fp8(v[4], v[5], v[6], v[7]);
      size_t ni = (size_t)(n0 >> 4) + nis;
      *(uint2*)(w18 + (((size_t)l*128 + ni)*3 + kt)*512 + lane*8) = o;
    }
    return;
  }
  bx -= W1_BLK_;
  {
    int k0 = (bx & 31) * 64, l = bx >> 5;
    for (int idx = tid; idx < 64*D_; idx += 256) {
      int k = idx / D_, n = idx % D_;
      t[k*D_ + n] = w2[((size_t)(l*FFN_ + k0 + k))*D_ + n];
    }
    __syncthreads();
    for (int idx = tid; idx < 5*2*64; idx += 256) {
      int nf = idx / 128, rem = idx % 128;
      int ktl = rem / 64, lane = rem % 64;
      int r = lane & 15, g = lane >> 4;
      int n = nf*16 + r;
      int kb = ktl*32 + g*8;
      uint2 o;
      o.x = pk4fp8(t[(kb+0)*D_+n]*16.f, t[(kb+1)*D_+n]*16.f, t[(kb+2)*D_+n]*16.f, t[(kb+3)*D_+n]*16.f);
      o.y = pk4fp8(t[(kb+4)*D_+n]*16.f, t[(kb+5)*D_+n]*16.f, t[(kb+6)*D_+n]*16.f, t[(kb+7)*D_+n]*16.f);
      size_t kt = (size_t)(k0 >> 5) + ktl;
      *(uint2*)(w28 + (((size_t)l*5 + nf)*64 + kt)*512 + lane*8) = o;
    }
  }
}

// ============ cooperative persistent model kernel: build + 4 layers ============
struct KArgs {
  const float* mel;
  const float* lnin_w; const float* lnin_b;
  const float* lnff_w; const float* lnff_b;
  const float* lno_w;  const float* lno_b;
  const float* bo; const float* b1; const float* b2;
  const float* bqkv; const float* pb;
  float* x;
  ushort_t* qb0; ushort_t* kvb0; ushort_t* qb1; ushort_t* kvb1;
  const ushort_t* wqkvT; const ushort_t* woT; const ushort_t* pwT;
  const uchar_t* w18; const uchar_t* w28;
  float* out;
};

#define POOLB_ 106240
__global__ __launch_bounds__(1024) void k_model(KArgs A) {
  cg::grid_group grid = cg::this_grid();
  int tid = threadIdx.x;
  int wv = tid >> 6, lane = tid & 63;
  int r = lane & 15, g = lane >> 4;
  int bm = blockIdx.x * 16;
  int b = bm / L_, i0 = bm % L_;

  __shared__ __align__(16) char pool[POOLB_];
  __shared__ ushort_t attsh[16][KP_];
  __shared__ ushort_t hnsh[16][KP_];
  __shared__ uchar_t  hn8[16][104];
  __shared__ float    resf[16][D_];
  __shared__ float    inv_sh[8][16];

  // attn-phase pool views
  ushort_t (*ksh)[90][D_] = (ushort_t(*)[90][D_])(pool);             // [2][90][80]
  ushort_t (*vsh)[90][D_] = (ushort_t(*)[90][D_])(pool + 28800);
  ushort_t (*qsh)[D_]     = (ushort_t(*)[D_])(pool + 57600);         // [16][80]
  float    (*Ssh)[16][90] = (float(*)[16][90])(pool + 60160);        // [8][16][90]
  // ffn-phase pool views
  uchar_t  (*ff18)[16][136] = (uchar_t(*)[16][136])(pool);           // [16][16][136]
  ushort_t (*redb)[16][D_]  = (ushort_t(*)[16][D_])(pool + 34816);   // [16][16][80]

  // ---- window setup (loop-invariant) ----
  int isR = (i0 < RCT_);
  int nw  = isR ? 2 : 1;
  int ws0 = isR ? (i0 >> 3) : ((i0 - RCT_) >> 5);
  int kcs[2], s0s[2];
  #pragma unroll
  for (int w = 0; w < 2; ++w) {
    int seg = ws0 + w;
    int s0 = seg*SEG_ - LC_; if (s0 < 0) s0 = 0;
    s0s[w] = s0;
    kcs[w] = RC_ + (seg+1)*SEG_ - s0;    // 40..90
  }

  // ======== build phase: gather + LN_in(0) -> hnsh, x; QKV(0) -> qb0/kvb0 ========
  if (tid < 256) {
    int row = tid >> 4, j = tid & 15;
    int grow = bm + row;
    int i = grow % L_;
    int srow = (i < RCT_) ? ((i >> 3) + 1)*SEG_ + (i & 7) : i - RCT_;
    float v[5], s = 0.f, ss = 0.f;
    #pragma unroll
    for (int c = 0; c < 5; ++c) {
      int col = j*5 + c;
      v[c] = A.mel[((size_t)b*(TU_+RC_) + srow)*D_ + col];
      A.x[(size_t)grow*D_ + col] = v[c];
      s += v[c]; ss += v[c]*v[c];
    }
    s  += __shfl_xor(s, 1, 16);  ss += __shfl_xor(ss, 1, 16);
    s  += __shfl_xor(s, 2, 16);  ss += __shfl_xor(ss, 2, 16);
    s  += __shfl_xor(s, 4, 16);  ss += __shfl_xor(ss, 4, 16);
    s  += __shfl_xor(s, 8, 16);  ss += __shfl_xor(ss, 8, 16);
    float mean = s * (1.f/D_);
    float var  = ss * (1.f/D_) - mean*mean;
    float inv  = rsqrtf(var + EPS_);
    #pragma unroll
    for (int c = 0; c < 5; ++c) {
      int col = j*5 + c;
      hnsh[row][col] = f2bf((v[c] - mean) * inv * A.lnin_w[col] + A.lnin_b[col]);
    }
    hnsh[row][D_ + j] = 0;
    attsh[row][D_ + j] = 0;     // pads stay zero for all layers
  }
  __syncthreads();
  if (wv < 15) {
    int t = wv;
    f32x4 acc = {};
    #pragma unroll
    for (int kt = 0; kt < 3; ++kt) {
      bf16x8 a  = *(const bf16x8*)(&hnsh[r][kt*32 + g*8]);
      bf16x8 bb = *(const bf16x8*)(A.wqkvT + ((size_t)t*3 + kt)*512 + lane*8);
      acc = __builtin_amdgcn_mfma_f32_16x16x32_bf16(a, bb, acc, 0, 0, 0);
    }
    int col = t*16 + r;
    float bc = A.bqkv[col];
    #pragma unroll
    for (int rr = 0; rr < 4; ++rr) {
      int row = bm + g*4 + rr;
      float v = acc[rr] + bc;
      if (col < D_) A.qb0[(size_t)row*D_ + col] = f2bf(v);
      else          A.kvb0[(size_t)row*2*D_ + (col - D_)] = f2bf(v);
    }
  }
  __threadfence();
  grid.sync();

  // ======== layer loop ========
  for (int l = 0; l < NLAYERS_; ++l) {
    int last = (l == NLAYERS_-1);
    const ushort_t* qin  = (l & 1) ? A.qb1  : A.qb0;
    const ushort_t* kvin = (l & 1) ? A.kvb1 : A.kvb0;
    ushort_t* qout  = (l & 1) ? A.qb0  : A.qb1;
    ushort_t* kvout = (l & 1) ? A.kvb0 : A.kvb1;
    const ushort_t* woTl = A.woT + l*15*512;
    const uchar_t* w18l = A.w18 + (size_t)l*FFN_*KP_;
    const uchar_t* w28l = A.w28 + (size_t)l*D_*FFN_;
    const float* bo_l = A.bo + l*D_;
    const float* b1_l = A.b1 + l*FFN_;
    const float* b2_l = A.b2 + l*D_;
    const float* lfw = A.lnff_w + l*D_;
    const float* lfb = A.lnff_b + l*D_;
    const float* low = A.lno_w + l*D_;
    const float* lob = A.lno_b + l*D_;
    const float* liw = A.lnin_w + (last ? 0 : (l+1)*D_);
    const float* lib = A.lnin_b + (last ? 0 : (l+1)*D_);
    const ushort_t* wqkvTn = A.wqkvT + (size_t)(last ? 0 : (l+1))*45*512;
    const float* bqkvn = A.bqkv + (last ? 0 : (l+1))*240;

    // ---- stage K/V windows (bf16) + Q ----
    for (int e = tid; e < nw*90*40; e += 1024) {
      int dd = (e % 40) * 2;
      int t2 = e / 40;
      int kk = t2 % 90, w = t2 / 90;
      if (kk < kcs[w]) {
        int seg = ws0 + w;
        int krow = (kk < RC_) ? seg*RC_ + kk : RCT_ + s0s[w] + (kk - RC_);
        const ushort_t* base = kvin + ((size_t)b*L_ + krow)*2*D_ + dd;
        *(ushort2*)&ksh[w][kk][dd] = *(const ushort2*)base;
        *(ushort2*)&vsh[w][kk][dd] = *(const ushort2*)(base + D_);
      }
    }
    if (tid < 640) {
      int row = tid / 40, dd = (tid % 40)*2;
      *(ushort2*)&qsh[row][dd] = *(const ushort2*)(qin + ((size_t)(bm+row))*D_ + dd);
    }
    __syncthreads();

    // ---- scores + softmax ----
    {
      int j = tid & 7, unit = tid >> 3;
      int row = unit & 15, h = unit >> 4;
      int w = isR ? (row >> 3) : 0;
      int kc = kcs[w];
      float qv[DH_];
      #pragma unroll
      for (int d = 0; d < DH_; ++d) qv[d] = bf2f(qsh[row][h*DH_ + d]);
      float pm = -INFINITY;
      for (int kk = j; kk < kc; kk += 8) {
        float s = 0.f;
        #pragma unroll
        for (int d = 0; d < DH_; ++d) s += qv[d] * bf2f(ksh[w][kk][h*DH_ + d]);
        Ssh[h][row][kk] = s;
        pm = fmaxf(pm, s);
      }
      pm = fmaxf(pm, __shfl_xor(pm, 1, 8));
      pm = fmaxf(pm, __shfl_xor(pm, 2, 8));
      pm = fmaxf(pm, __shfl_xor(pm, 4, 8));
      float ps = 0.f;
      for (int kk = j; kk < kc; kk += 8) {
        float e = __expf(Ssh[h][row][kk] - pm);
        Ssh[h][row][kk] = e;
        ps += e;
      }
      ps += __shfl_xor(ps, 1, 8);
      ps += __shfl_xor(ps, 2, 8);
      ps += __shfl_xor(ps, 4, 8);
      if (j == 0) inv_sh[h][row] = 1.f / ps;
    }
    __syncthreads();

    // ---- PV -> attsh bf16 ----
    if (tid < 640) {
      int dp = tid % 5, u = tid / 5;
      int row = u & 15, h = u >> 4;
      int w = isR ? (row >> 3) : 0;
      int kc = kcs[w];
      int d0 = dp*2;
      float a0 = 0.f, a1 = 0.f;
      for (int kk = 0; kk < kc; ++kk) {
        float p = Ssh[h][row][kk];
        a0 += p * bf2f(vsh[w][kk][h*DH_ + d0]);
        a1 += p * bf2f(vsh[w][kk][h*DH_ + d0 + 1]);
      }
      float invl = inv_sh[h][row];
      attsh[row][h*DH_ + d0]     = f2bf(a0 * invl);
      attsh[row][h*DH_ + d0 + 1] = f2bf(a1 * invl);
    }
    __syncthreads();

    // ---- WO split over 15 waves -> redb ----
    if (wv < 15) {
      int nf = wv / 3, kt = wv % 3;
      f32x4 acc = {};
      bf16x8 a  = *(const bf16x8*)(&attsh[r][kt*32 + g*8]);
      bf16x8 bb = *(const bf16x8*)(woTl + ((size_t)nf*3 + kt)*512 + lane*8);
      acc = __builtin_amdgcn_mfma_f32_16x16x32_bf16(a, bb, acc, 0, 0, 0);
      #pragma unroll
      for (int rr = 0; rr < 4; ++rr)
        redb[wv][g*4 + rr][nf*16 + r] = f2bf(acc[rr]);
    }
    __syncthreads();

    // ---- WO sum + bias + residual + LN_ff -> hn8 (res in resf) ----
    if (tid < 256) {
      int row = tid >> 4, j = tid & 15;
      int grow = bm + row;
      float v[5], s = 0.f, ss = 0.f;
      #pragma unroll
      for (int c = 0; c < 5; ++c) {
        int col = j*5 + c;
        int nf3 = (col >> 4) * 3;
        float wo3 = bf2f(redb[nf3][row][col]) + bf2f(redb[nf3+1][row][col])
                  + bf2f(redb[nf3+2][row][col]);
        v[c] = wo3 + bo_l[col] + A.x[(size_t)grow*D_ + col];
        resf[row][col] = v[c];
        s += v[c]; ss += v[c]*v[c];
      }
      s  += __shfl_xor(s, 1, 16);  ss += __shfl_xor(ss, 1, 16);
      s  += __shfl_xor(s, 2, 16);  ss += __shfl_xor(ss, 2, 16);
      s  += __shfl_xor(s, 4, 16);  ss += __shfl_xor(ss, 4, 16);
      s  += __shfl_xor(s, 8, 16);  ss += __shfl_xor(ss, 8, 16);
      float mean = s * (1.f/D_);
      float var  = ss * (1.f/D_) - mean*mean;
      float inv  = rsqrtf(var + EPS_);
      #pragma unroll
      for (int c = 0; c < 5; ++c) {
        int col = j*5 + c;
        hn8[row][col] = f2fp8((v[c] - mean) * inv * lfw[col] + lfb[col]);
      }
      hn8[row][D_ + j] = 0;
    }
    __syncthreads();

    // ---- FFN1 fp8 ----
    f32x4 acc1[8];
    #pragma unroll
    for (int ni = 0; ni < 8; ++ni) acc1[ni] = (f32x4){0.f,0.f,0.f,0.f};
    #pragma unroll
    for (int kt = 0; kt < 3; ++kt) {
      i64_t a = *(const i64_t*)(&hn8[r][kt*32 + g*8]);
      #pragma unroll
      for (int ni = 0; ni < 8; ++ni) {
        i64_t bb = *(const i64_t*)(w18l + (((size_t)(wv*8 + ni))*3 + kt)*512 + lane*8);
        acc1[ni] = __builtin_amdgcn_mfma_f32_16x16x32_fp8_fp8(a, bb, acc1[ni], 0, 0, 0);
      }
    }
    int nbase = wv*128;
    #pragma unroll
    for (int ni = 0; ni < 8; ++ni) {
      int col = nbase + ni*16 + r;
      float bc = b1_l[col];
      #pragma unroll
      for (int rr = 0; rr < 4; ++rr) {
        float v = acc1[ni][rr] * 0.0625f + bc;
        ff18[wv][g*4 + rr][ni*16 + r] = f2fp8(fmaxf(v, 0.f) * 8.f);
      }
    }
    // same-wave write->read of ff18[wv]: compiler-ordered

    // ---- FFN2 fp8 ----
    f32x4 acc2[5] = {};
    #pragma unroll
    for (int ks = 0; ks < 4; ++ks) {
      i64_t a = *(const i64_t*)(&ff18[wv][r][ks*32 + g*8]);
      #pragma unroll
      for (int nf = 0; nf < 5; ++nf) {
        i64_t bb = *(const i64_t*)(w28l + (((size_t)nf*64) + wv*4 + ks)*512 + lane*8);
        acc2[nf] = __builtin_amdgcn_mfma_f32_16x16x32_fp8_fp8(a, bb, acc2[nf], 0, 0, 0);
      }
    }
    __syncthreads();
    #pragma unroll
    for (int nf = 0; nf < 5; ++nf)
      #pragma unroll
      for (int rr = 0; rr < 4; ++rr)
        redb[wv][g*4 + rr][nf*16 + r] = f2bf(acc2[nf][rr]);
    __syncthreads();

    for (int e = tid; e < 16*D_; e += 1024) {
      int row = e / D_, col = e % D_;
      float s0 = 0.f, s1 = 0.f, s2 = 0.f, s3 = 0.f;
      #pragma unroll
      for (int w = 0; w < 16; w += 4) {
        s0 += bf2f(redb[w+0][row][col]);
        s1 += bf2f(redb[w+1][row][col]);
        s2 += bf2f(redb[w+2][row][col]);
        s3 += bf2f(redb[w+3][row][col]);
      }
      resf[row][col] = ((s0+s1)+(s2+s3)) * (1.f/128.f) + b2_l[col] + resf[row][col];
    }
    __syncthreads();
    if (tid < 256) {
      int row = tid >> 4, j = tid & 15;
      float v[5], s = 0.f, ss = 0.f;
      #pragma unroll
      for (int c = 0; c < 5; ++c) {
        v[c] = resf[row][j*5 + c];
        s += v[c]; ss += v[c]*v[c];
      }
      s  += __shfl_xor(s, 1, 16);  ss += __shfl_xor(ss, 1, 16);
      s  += __shfl_xor(s, 2, 16);  ss += __shfl_xor(ss, 2, 16);
      s  += __shfl_xor(s, 4, 16);  ss += __shfl_xor(ss, 4, 16);
      s  += __shfl_xor(s, 8, 16);  ss += __shfl_xor(ss, 8, 16);
      float mean = s * (1.f/D_);
      float var  = ss * (1.f/D_) - mean*mean;
      float inv  = rsqrtf(var + EPS_);
      int grow = bm + row;
      float xs[5];
      float s2 = 0.f, ss2 = 0.f;
      #pragma unroll
      for (int c = 0; c < 5; ++c) {
        int col = j*5 + c;
        xs[c] = (v[c] - mean) * inv * low[col] + lob[col];
        A.x[(size_t)grow*D_ + col] = xs[c];
        s2 += xs[c]; ss2 += xs[c]*xs[c];
      }
      if (!last) {
        s2  += __shfl_xor(s2, 1, 16);  ss2 += __shfl_xor(ss2, 1, 16);
        s2  += __shfl_xor(s2, 2, 16);  ss2 += __shfl_xor(ss2, 2, 16);
        s2  += __shfl_xor(s2, 4, 16);  ss2 += __shfl_xor(ss2, 4, 16);
        s2  += __shfl_xor(s2, 8, 16);  ss2 += __shfl_xor(ss2, 8, 16);
        float m2 = s2 * (1.f/D_);
        float v2 = ss2 * (1.f/D_) - m2*m2;
        float i2 = rsqrtf(v2 + EPS_);
        #pragma unroll
        for (int c = 0; c < 5; ++c) {
          int col = j*5 + c;
          hnsh[row][col] = f2bf((xs[c] - m2) * i2 * liw[col] + lib[col]);
        }
      } else {
        #pragma unroll
        for (int c = 0; c < 5; ++c)
          hnsh[row][j*5 + c] = f2bf(xs[c]);
      }
      hnsh[row][D_ + j] = 0;
    }

    if (!last) {
      // ---- next-layer QKV -> qout/kvout (double-buffered) ----
      __syncthreads();
      if (wv < 15) {
        int t = wv;
        f32x4 acc = {};
        #pragma unroll
        for (int kt = 0; kt < 3; ++kt) {
          bf16x8 a  = *(const bf16x8*)(&hnsh[r][kt*32 + g*8]);
          bf16x8 bb = *(const bf16x8*)(wqkvTn + ((size_t)t*3 + kt)*512 + lane*8);
          acc = __builtin_amdgcn_mfma_f32_16x16x32_bf16(a, bb, acc, 0, 0, 0);
        }
        int col = t*16 + r;
        float bc = bqkvn[col];
        #pragma unroll
        for (int rr = 0; rr < 4; ++rr) {
          int row = bm + g*4 + rr;
          float v = acc[rr] + bc;
          if (col < D_) qout[(size_t)row*D_ + col] = f2bf(v);
          else          kvout[(size_t)row*2*D_ + (col - D_)] = f2bf(v);
        }
      }
      __threadfence();
      grid.sync();
    } else {
      // ---- final projection: u-rows only ----
      __syncthreads();
      if (i0 >= RCT_) {
        int urow0 = i0 - RCT_;
        for (int t = wv; t < 48; t += 16) {
          f32x4 acc = {};
          #pragma unroll
          for (int kt = 0; kt < 3; ++kt) {
            bf16x8 a  = *(const bf16x8*)(&hnsh[r][kt*32 + g*8]);
            bf16x8 bb = *(const bf16x8*)(A.pwT + ((size_t)t*3 + kt)*512 + lane*8);
            acc = __builtin_amdgcn_mfma_f32_16x16x32_bf16(a, bb, acc, 0, 0, 0);
          }
          int col = t*16 + r;
          float bc = A.pb[col];
          #pragma unroll
          for (int rr = 0; rr < 4; ++rr) {
            int row = urow0 + g*4 + rr;
            A.out[((size_t)b*TU_ + row)*OUTD_ + col] = acc[rr] + bc;
          }
        }
      }
    }
  }
}

extern "C" void kernel_launch(void* const* d_in, const int* in_sizes, int n_in,
                              void* d_out, int out_size, void* d_ws, size_t ws_size,
                              hipStream_t stream) {
  const float* mel     = (const float*)d_in[0];
  const int*   lengths = (const int*)  d_in[1];
  const float* ln_in_w = (const float*)d_in[2];
  const float* ln_in_b = (const float*)d_in[3];
  const float* wq      = (const float*)d_in[4];
  const float* bq      = (const float*)d_in[5];
  const float* wkv     = (const float*)d_in[6];
  const float* bkv     = (const float*)d_in[7];
  const float* wo      = (const float*)d_in[8];
  const float* bo      = (const float*)d_in[9];
  const float* ln_ff_w = (const float*)d_in[10];
  const float* ln_ff_b = (const float*)d_in[11];
  const float* w1      = (const float*)d_in[12];
  const float* b1      = (const float*)d_in[13];
  const float* w2      = (const float*)d_in[14];
  const float* b2      = (const float*)d_in[15];
  const float* ln_o_w  = (const float*)d_in[16];
  const float* ln_o_b  = (const float*)d_in[17];
  const float* pw      = (const float*)d_in[18];
  const float* pb      = (const float*)d_in[19];
  float* out = (float*)d_out;

  float* ws = (float*)d_ws;
  float* x     = ws; ws += NR_*D_;
  float* bqkv  = ws; ws += NLAYERS_*240;
  ushort_t* us = (ushort_t*)ws;
  ushort_t* qb0   = us; us += NR_*D_;
  ushort_t* kvb0  = us; us += NR_*2*D_;
  ushort_t* qb1   = us; us += NR_*D_;
  ushort_t* kvb1  = us; us += NR_*2*D_;
  ushort_t* wqkvT = us; us += S3_;
  ushort_t* woT   = us; us += S4_;
  ushort_t* pwT   = us; us += S5_;
  uchar_t* ub = (uchar_t*)us;
  uchar_t* w18 = ub; ub += S1_;
  uchar_t* w28 = ub; ub += S2_;

  k_wprep_all<<<WSM_BLK_ + W1_BLK_ + W2_BLK_, 256, 0, stream>>>(
      wq, wkv, wo, pw, bq, bkv, w1, w2, wqkvT, woT, pwT, bqkv, w18, w28,
      lengths, out);

  KArgs A;
  A.mel = mel;
  A.lnin_w = ln_in_w; A.lnin_b = ln_in_b;
  A.lnff_w = ln_ff_w; A.lnff_b = ln_ff_b;
  A.lno_w = ln_o_w;   A.lno_b = ln_o_b;
  A.bo = bo; A.b1 = b1; A.b2 = b2;
  A.bqkv = bqkv; A.pb = pb;
  A.x = x;
  A.qb0 = qb0; A.kvb0 = kvb0; A.qb1 = qb1; A.kvb1 = kvb1;
  A.wqkvT = wqkvT; A.woT = woT; A.pwT = pwT;
  A.w18 = w18; A.w28 = w28;
  A.out = out;
  void* params[] = { &A };
  hipLaunchCooperativeKernel((void*)k_model, dim3(NR_/16), dim3(1024),
                             params, 0, stream);
}

// Round 20
// 95.621 us; speedup vs baseline: 4.6414x; 4.6414x over previous
//
#include <hip/hip_runtime.h>
#include <math.h>

#define B_    2
#define TU_   1024
#define D_    80
#define H_    8
#define DH_   10
#define FFN_  2048
#define SEG_  32
#define RC_   8
#define LC_   50
#define NSEG_ 32
#define RCT_  256
#define L_    1280
#define NLAYERS_ 4
#define OUTD_ 768
#define EPS_  1e-5f
#define SCALE_ 0.31622776601683794f
#define NR_   (B_*L_)                 // 2560
#define KP_   96                      // K pad 80->96

typedef __attribute__((ext_vector_type(8))) short bf16x8;
typedef __attribute__((ext_vector_type(4))) float f32x4;
typedef unsigned short ushort_t;
typedef unsigned char uchar_t;
typedef long i64_t;

__device__ inline ushort_t f2bf(float f) {
  union { float f; unsigned u; } x; x.f = f;
  unsigned r = x.u + 0x7fffu + ((x.u >> 16) & 1u);   // RNE
  return (ushort_t)(r >> 16);
}
__device__ inline float bf2f(ushort_t u) {
  union { unsigned u; float f; } x; x.u = ((unsigned)u) << 16; return x.f;
}
__device__ inline uchar_t f2fp8(float f) {
  return (uchar_t)(__builtin_amdgcn_cvt_pk_fp8_f32(f, f, 0, false) & 0xff);
}
__device__ inline unsigned pk4fp8(float f0, float f1, float f2, float f3) {
  unsigned w = (unsigned)__builtin_amdgcn_cvt_pk_fp8_f32(f0, f1, 0, false);
  w = (unsigned)__builtin_amdgcn_cvt_pk_fp8_f32(f2, f3, (int)w, true);
  return w;
}

// ---- fragment-tiled sizes (tile = 512 elements = 64 lanes x 8) ----
#define S1_  (NLAYERS_*FFN_*KP_)       // w18 fp8 tiled [l][128 ntile][3 ktile][512]
#define S2_  (NLAYERS_*D_*FFN_)        // w28 fp8 tiled [l][5 ntile][64 ktile][512]
#define S3_  (NLAYERS_*45*512)         // wqkvT bf16 tiled [l][15][3][512]
#define S4_  (NLAYERS_*15*512)         // woT bf16 tiled [l][5][3][512]
#define S5_  (144*512)                 // pwT bf16 tiled [48][3][512]
#define S6_  (NLAYERS_*240)            // bqkv fp32
#define WSM_N_ (S3_+S4_+S5_+S6_)
#define WSM_BLK_ ((WSM_N_ + 255)/256)          // 772
#define W1_BLK_  (32*NLAYERS_)                 // 128
#define W2_BLK_  (32*NLAYERS_)                 // 128

// ============ unified weight prep (+ lengths tail) ============
__global__ __launch_bounds__(256) void k_wprep_all(
    const float* __restrict__ wq, const float* __restrict__ wkv,
    const float* __restrict__ wo, const float* __restrict__ pw,
    const float* __restrict__ bq, const float* __restrict__ bkv,
    const float* __restrict__ w1, const float* __restrict__ w2,
    ushort_t* __restrict__ wqkvT, ushort_t* __restrict__ woT,
    ushort_t* __restrict__ pwT, float* __restrict__ bqkv,
    uchar_t* __restrict__ w18, uchar_t* __restrict__ w28,
    const int* __restrict__ len, float* __restrict__ out) {
  int bx = blockIdx.x;
  int tid = threadIdx.x;
  __shared__ float t[5120];

  if (bx == 0 && tid < B_)
    out[(size_t)B_*TU_*OUTD_ + tid] = (float)len[tid];

  if (bx < WSM_BLK_) {
    int idx = bx * 256 + tid;
    if (idx < S3_) {
      int l = idx / (45*512); int rem = idx % (45*512);
      int tile = rem / 512, off = rem % 512;
      int tt = tile / 3, kt = tile % 3;
      int lane = off >> 3, j = off & 7;
      int n = tt*16 + (lane & 15);
      int k = kt*32 + (lane >> 4)*8 + j;
      float v = 0.f;
      if (k < D_) {
        if (n < D_)       v = wq[(l*D_ + k)*D_ + n] * SCALE_;
        else if (n < 240) v = wkv[(l*D_ + k)*2*D_ + (n - D_)];
      }
      wqkvT[idx] = f2bf(v);
      return;
    }
    idx -= S3_;
    if (idx < S4_) {
      int l = idx / (15*512); int rem = idx % (15*512);
      int tile = rem / 512, off = rem % 512;
      int nf = tile / 3, kt = tile % 3;
      int lane = off >> 3, j = off & 7;
      int n = nf*16 + (lane & 15);
      int k = kt*32 + (lane >> 4)*8 + j;
      woT[idx] = (k < D_) ? f2bf(wo[(l*D_ + k)*D_ + n]) : 0;
      return;
    }
    idx -= S4_;
    if (idx < S5_) {
      int tile = idx / 512, off = idx % 512;
      int tt = tile / 3, kt = tile % 3;
      int lane = off >> 3, j = off & 7;
      int n = tt*16 + (lane & 15);
      int k = kt*32 + (lane >> 4)*8 + j;
      pwT[idx] = (k < D_) ? f2bf(pw[k*OUTD_ + n]) : 0;
      return;
    }
    idx -= S5_;
    if (idx < S6_) {
      int c = idx % 240, l = idx / 240;
      bqkv[idx] = (c < D_) ? bq[l*D_ + c] * SCALE_ : bkv[l*2*D_ + (c - D_)];
    }
    return;
  }
  bx -= WSM_BLK_;
  if (bx < W1_BLK_) {
    int n0 = (bx & 31) * 64, l = bx >> 5;
    for (int idx = tid; idx < D_*64; idx += 256) {
      int k = idx >> 6, n = idx & 63;
      t[k*64 + n] = w1[((size_t)(l*D_ + k))*FFN_ + n0 + n];
    }
    __syncthreads();
    for (int idx = tid; idx < 4*3*64; idx += 256) {
      int nis = idx / 192, rem = idx % 192;
      int kt = rem / 64, lane = rem % 64;
      int r = lane & 15, g = lane >> 4;
      int nl = nis*16 + r;
      int kb = kt*32 + g*8;
      float v[8];
      #pragma unroll
      for (int j = 0; j < 8; ++j) {
        int k = kb + j;
        v[j] = (k < D_) ? t[k*64 + nl]*16.f : 0.f;
      }
      uint2 o;
      o.x = pk4fp8(v[0], v[1], v[2], v[3]);
      o.y = pk4fp8(v[4], v[5], v[6], v[7]);
      size_t ni = (size_t)(n0 >> 4) + nis;
      *(uint2*)(w18 + (((size_t)l*128 + ni)*3 + kt)*512 + lane*8) = o;
    }
    return;
  }
  bx -= W1_BLK_;
  {
    int k0 = (bx & 31) * 64, l = bx >> 5;
    for (int idx = tid; idx < 64*D_; idx += 256) {
      int k = idx / D_, n = idx % D_;
      t[k*D_ + n] = w2[((size_t)(l*FFN_ + k0 + k))*D_ + n];
    }
    __syncthreads();
    for (int idx = tid; idx < 5*2*64; idx += 256) {
      int nf = idx / 128, rem = idx % 128;
      int ktl = rem / 64, lane = rem % 64;
      int r = lane & 15, g = lane >> 4;
      int n = nf*16 + r;
      int kb = ktl*32 + g*8;
      uint2 o;
      o.x = pk4fp8(t[(kb+0)*D_+n]*16.f, t[(kb+1)*D_+n]*16.f, t[(kb+2)*D_+n]*16.f, t[(kb+3)*D_+n]*16.f);
      o.y = pk4fp8(t[(kb+4)*D_+n]*16.f, t[(kb+5)*D_+n]*16.f, t[(kb+6)*D_+n]*16.f, t[(kb+7)*D_+n]*16.f);
      size_t kt = (size_t)(k0 >> 5) + ktl;
      *(uint2*)(w28 + (((size_t)l*5 + nf)*64 + kt)*512 + lane*8) = o;
    }
  }
}

// ============ merged: gather mel -> x + layer-0 LN_in + QKV MFMA -> q/kv (bf16) ============
__global__ __launch_bounds__(512) void k_build_qkv(const float* __restrict__ mel,
    const float* __restrict__ lw, const float* __restrict__ lb,
    const ushort_t* __restrict__ wqkvT, const float* __restrict__ bqkv,
    float* __restrict__ x, ushort_t* __restrict__ q, ushort_t* __restrict__ kv) {
  int tid = threadIdx.x;
  int wv = tid >> 6, lane = tid & 63;
  int r = lane & 15, g = lane >> 4;
  int bm = blockIdx.x * 16;
  __shared__ ushort_t hnsh[16][KP_];

  if (tid < 256) {
    int row = tid >> 4, j = tid & 15;
    int grow = bm + row;
    int b = grow / L_, i = grow % L_;
    int srow = (i < RCT_) ? ((i >> 3) + 1)*SEG_ + (i & 7) : i - RCT_;
    float v[5], s = 0.f, ss = 0.f;
    #pragma unroll
    for (int c = 0; c < 5; ++c) {
      int col = j*5 + c;
      v[c] = mel[((size_t)b*(TU_+RC_) + srow)*D_ + col];
      x[(size_t)grow*D_ + col] = v[c];
      s += v[c]; ss += v[c]*v[c];
    }
    s  += __shfl_xor(s, 1, 16);  ss += __shfl_xor(ss, 1, 16);
    s  += __shfl_xor(s, 2, 16);  ss += __shfl_xor(ss, 2, 16);
    s  += __shfl_xor(s, 4, 16);  ss += __shfl_xor(ss, 4, 16);
    s  += __shfl_xor(s, 8, 16);  ss += __shfl_xor(ss, 8, 16);
    float mean = s * (1.f/D_);
    float var  = ss * (1.f/D_) - mean*mean;
    float inv  = rsqrtf(var + EPS_);
    #pragma unroll
    for (int c = 0; c < 5; ++c) {
      int col = j*5 + c;
      hnsh[row][col] = f2bf((v[c] - mean) * inv * lw[col] + lb[col]);
    }
    hnsh[row][D_ + j] = 0;
  }
  __syncthreads();

  for (int t = wv; t < 15; t += 8) {
    f32x4 acc = {};
    #pragma unroll
    for (int kt = 0; kt < 3; ++kt) {
      bf16x8 a  = *(const bf16x8*)(&hnsh[r][kt*32 + g*8]);
      bf16x8 bb = *(const bf16x8*)(wqkvT + ((size_t)t*3 + kt)*512 + lane*8);
      acc = __builtin_amdgcn_mfma_f32_16x16x32_bf16(a, bb, acc, 0, 0, 0);
    }
    int col = t*16 + r;
    float bc = bqkv[col];
    #pragma unroll
    for (int rr = 0; rr < 4; ++rr) {
      int row = bm + g*4 + rr;
      float v = acc[rr] + bc;
      if (col < D_) q[(size_t)row*D_ + col] = f2bf(v);
      else          kv[(size_t)row*2*D_ + (col - D_)] = f2bf(v);
    }
  }
}

// ============ per-layer mega kernel: attention(own 16 rows, 1 pass, bf16 staging)
//              + WO + LN_ff + FFN1(fp8) + FFN2(fp8) + LN_out
//              + (mode0: QKV(next) -> qout/kvout | mode1: final projection) ============
// grid 160, 1024 thr. Attn pools union with FFN pools (disjoint lifetimes).
#define POOLB_ 106240
__global__ __launch_bounds__(1024) void k_layer(
    const ushort_t* __restrict__ qin, const ushort_t* __restrict__ kvin,
    const ushort_t* __restrict__ woT, const float* __restrict__ bo,
    const uchar_t* __restrict__ w18, const float* __restrict__ b1,
    const uchar_t* __restrict__ w28, const float* __restrict__ b2,
    const float* __restrict__ lfw, const float* __restrict__ lfb,
    const float* __restrict__ low, const float* __restrict__ lob,
    const float* __restrict__ liw, const float* __restrict__ lib, int mode,
    float* __restrict__ x,
    const ushort_t* __restrict__ wqkvT_n, const float* __restrict__ bqkv_n,
    ushort_t* __restrict__ qout, ushort_t* __restrict__ kvout,
    const ushort_t* __restrict__ pwT, const float* __restrict__ pb,
    float* __restrict__ out) {
  int tid = threadIdx.x;
  int wv = tid >> 6, lane = tid & 63;
  int r = lane & 15, g = lane >> 4;
  int bm = blockIdx.x * 16;
  int b = bm / L_, i0 = bm % L_;

  __shared__ __align__(16) char pool[POOLB_];
  __shared__ ushort_t attsh[16][KP_];
  __shared__ ushort_t hnsh[16][KP_];
  __shared__ uchar_t  hn8[16][104];
  __shared__ float    resf[16][D_];
  __shared__ float    inv_sh[8][16];

  // attn-phase pool views
  ushort_t (*ksh)[90][D_] = (ushort_t(*)[90][D_])(pool);             // [2][90][80]
  ushort_t (*vsh)[90][D_] = (ushort_t(*)[90][D_])(pool + 28800);
  ushort_t (*qsh)[D_]     = (ushort_t(*)[D_])(pool + 57600);         // [16][80]
  float    (*Ssh)[16][90] = (float(*)[16][90])(pool + 60160);        // [8][16][90]
  // ffn-phase pool views (after attention completes)
  uchar_t  (*ff18)[16][136] = (uchar_t(*)[16][136])(pool);           // [16][16][136]
  ushort_t (*redb)[16][D_]  = (ushort_t(*)[16][D_])(pool + 34816);   // [16][16][80]

  // ---- window setup ----
  int isR = (i0 < RCT_);
  int nw  = isR ? 2 : 1;
  int ws0 = isR ? (i0 >> 3) : ((i0 - RCT_) >> 5);
  int kcs[2], s0s[2];
  #pragma unroll
  for (int w = 0; w < 2; ++w) {
    int seg = ws0 + w;
    int s0 = seg*SEG_ - LC_; if (s0 < 0) s0 = 0;
    s0s[w] = s0;
    kcs[w] = RC_ + (seg+1)*SEG_ - s0;    // 40..90
  }

  // ---- stage K/V windows (bf16, ushort2) + Q + zero attsh pads ----
  for (int e = tid; e < nw*90*40; e += 1024) {
    int dd = (e % 40) * 2;
    int t2 = e / 40;
    int kk = t2 % 90, w = t2 / 90;
    if (kk < kcs[w]) {
      int seg = ws0 + w;
      int krow = (kk < RC_) ? seg*RC_ + kk : RCT_ + s0s[w] + (kk - RC_);
      const ushort_t* base = kvin + ((size_t)b*L_ + krow)*2*D_ + dd;
      *(ushort2*)&ksh[w][kk][dd] = *(const ushort2*)base;
      *(ushort2*)&vsh[w][kk][dd] = *(const ushort2*)(base + D_);
    }
  }
  if (tid < 640) {
    int row = tid / 40, dd = (tid % 40)*2;
    *(ushort2*)&qsh[row][dd] = *(const ushort2*)(qin + ((size_t)(bm+row))*D_ + dd);
  }
  if (tid < 256) attsh[tid >> 4][D_ + (tid & 15)] = 0;
  __syncthreads();

  // ---- scores + softmax: 128 (row,head) units x 8 lanes (all 1024 thr) ----
  {
    int j = tid & 7, unit = tid >> 3;
    int row = unit & 15, h = unit >> 4;
    int w = isR ? (row >> 3) : 0;
    int kc = kcs[w];
    float qv[DH_];
    #pragma unroll
    for (int d = 0; d < DH_; ++d) qv[d] = bf2f(qsh[row][h*DH_ + d]);
    float pm = -INFINITY;
    for (int kk = j; kk < kc; kk += 8) {
      float s = 0.f;
      #pragma unroll
      for (int d = 0; d < DH_; ++d) s += qv[d] * bf2f(ksh[w][kk][h*DH_ + d]);
      Ssh[h][row][kk] = s;
      pm = fmaxf(pm, s);
    }
    pm = fmaxf(pm, __shfl_xor(pm, 1, 8));
    pm = fmaxf(pm, __shfl_xor(pm, 2, 8));
    pm = fmaxf(pm, __shfl_xor(pm, 4, 8));
    float ps = 0.f;
    for (int kk = j; kk < kc; kk += 8) {
      float e = __expf(Ssh[h][row][kk] - pm);
      Ssh[h][row][kk] = e;
      ps += e;
    }
    ps += __shfl_xor(ps, 1, 8);
    ps += __shfl_xor(ps, 2, 8);
    ps += __shfl_xor(ps, 4, 8);
    if (j == 0) inv_sh[h][row] = 1.f / ps;
  }
  __syncthreads();

  // ---- PV: 640 threads (row, head, d-pair) -> attsh bf16 ----
  if (tid < 640) {
    int dp = tid % 5, u = tid / 5;
    int row = u & 15, h = u >> 4;
    int w = isR ? (row >> 3) : 0;
    int kc = kcs[w];
    int d0 = dp*2;
    float a0 = 0.f, a1 = 0.f;
    for (int kk = 0; kk < kc; ++kk) {
      float p = Ssh[h][row][kk];
      a0 += p * bf2f(vsh[w][kk][h*DH_ + d0]);
      a1 += p * bf2f(vsh[w][kk][h*DH_ + d0 + 1]);
    }
    float invl = inv_sh[h][row];
    attsh[row][h*DH_ + d0]     = f2bf(a0 * invl);
    attsh[row][h*DH_ + d0 + 1] = f2bf(a1 * invl);
  }
  __syncthreads();

  // ---- WO split over 15 waves: wave = (nf, kt), bf16 partials in redb ----
  if (wv < 15) {
    int nf = wv / 3, kt = wv % 3;
    f32x4 acc = {};
    bf16x8 a  = *(const bf16x8*)(&attsh[r][kt*32 + g*8]);
    bf16x8 bb = *(const bf16x8*)(woT + ((size_t)nf*3 + kt)*512 + lane*8);
    acc = __builtin_amdgcn_mfma_f32_16x16x32_bf16(a, bb, acc, 0, 0, 0);
    #pragma unroll
    for (int rr = 0; rr < 4; ++rr)
      redb[wv][g*4 + rr][nf*16 + r] = f2bf(acc[rr]);
  }
  __syncthreads();

  // ---- sum 3 kt-partials + bias + residual + LN_ff -> hn8 (res kept in resf) ----
  if (tid < 256) {
    int row = tid >> 4, j = tid & 15;
    int grow = bm + row;
    float v[5], s = 0.f, ss = 0.f;
    #pragma unroll
    for (int c = 0; c < 5; ++c) {
      int col = j*5 + c;
      int nf3 = (col >> 4) * 3;
      float wo3 = bf2f(redb[nf3][row][col]) + bf2f(redb[nf3+1][row][col])
                + bf2f(redb[nf3+2][row][col]);
      v[c] = wo3 + bo[col] + x[(size_t)grow*D_ + col];
      resf[row][col] = v[c];
      s += v[c]; ss += v[c]*v[c];
    }
    s  += __shfl_xor(s, 1, 16);  ss += __shfl_xor(ss, 1, 16);
    s  += __shfl_xor(s, 2, 16);  ss += __shfl_xor(ss, 2, 16);
    s  += __shfl_xor(s, 4, 16);  ss += __shfl_xor(ss, 4, 16);
    s  += __shfl_xor(s, 8, 16);  ss += __shfl_xor(ss, 8, 16);
    float mean = s * (1.f/D_);
    float var  = ss * (1.f/D_) - mean*mean;
    float inv  = rsqrtf(var + EPS_);
    #pragma unroll
    for (int c = 0; c < 5; ++c) {
      int col = j*5 + c;
      hn8[row][col] = f2fp8((v[c] - mean) * inv * lfw[col] + lfb[col]);
    }
    hn8[row][D_ + j] = 0;
  }
  __syncthreads();

  // ---- FFN1 fp8: fragment-tiled w18 ----
  f32x4 acc1[8];
  #pragma unroll
  for (int ni = 0; ni < 8; ++ni) acc1[ni] = (f32x4){0.f,0.f,0.f,0.f};
  #pragma unroll
  for (int kt = 0; kt < 3; ++kt) {
    i64_t a = *(const i64_t*)(&hn8[r][kt*32 + g*8]);
    #pragma unroll
    for (int ni = 0; ni < 8; ++ni) {
      i64_t bb = *(const i64_t*)(w18 + (((size_t)(wv*8 + ni))*3 + kt)*512 + lane*8);
      acc1[ni] = __builtin_amdgcn_mfma_f32_16x16x32_fp8_fp8(a, bb, acc1[ni], 0, 0, 0);
    }
  }
  int nbase = wv*128;
  #pragma unroll
  for (int ni = 0; ni < 8; ++ni) {
    int col = nbase + ni*16 + r;
    float bc = b1[col];
    #pragma unroll
    for (int rr = 0; rr < 4; ++rr) {
      float v = acc1[ni][rr] * 0.0625f + bc;
      ff18[wv][g*4 + rr][ni*16 + r] = f2fp8(fmaxf(v, 0.f) * 8.f);
    }
  }
  // same-wave write->read of ff18[wv]: compiler-ordered

  // ---- FFN2 fp8 ----
  f32x4 acc2[5] = {};
  #pragma unroll
  for (int ks = 0; ks < 4; ++ks) {
    i64_t a = *(const i64_t*)(&ff18[wv][r][ks*32 + g*8]);
    #pragma unroll
    for (int nf = 0; nf < 5; ++nf) {
      i64_t bb = *(const i64_t*)(w28 + (((size_t)nf*64) + wv*4 + ks)*512 + lane*8);
      acc2[nf] = __builtin_amdgcn_mfma_f32_16x16x32_fp8_fp8(a, bb, acc2[nf], 0, 0, 0);
    }
  }
  __syncthreads();   // all ff18 reads done before redb (overlapping pool) is rewritten
  #pragma unroll
  for (int nf = 0; nf < 5; ++nf)
    #pragma unroll
    for (int rr = 0; rr < 4; ++rr)
      redb[wv][g*4 + rr][nf*16 + r] = f2bf(acc2[nf][rr]);
  __syncthreads();

  for (int e = tid; e < 16*D_; e += 1024) {
    int row = e / D_, col = e % D_;
    float s0 = 0.f, s1 = 0.f, s2 = 0.f, s3 = 0.f;
    #pragma unroll
    for (int w = 0; w < 16; w += 4) {
      s0 += bf2f(redb[w+0][row][col]);
      s1 += bf2f(redb[w+1][row][col]);
      s2 += bf2f(redb[w+2][row][col]);
      s3 += bf2f(redb[w+3][row][col]);
    }
    resf[row][col] = ((s0+s1)+(s2+s3)) * (1.f/128.f) + b2[col] + resf[row][col];
  }
  __syncthreads();
  if (tid < 256) {
    int row = tid >> 4, j = tid & 15;
    float v[5], s = 0.f, ss = 0.f;
    #pragma unroll
    for (int c = 0; c < 5; ++c) {
      v[c] = resf[row][j*5 + c];
      s += v[c]; ss += v[c]*v[c];
    }
    s  += __shfl_xor(s, 1, 16);  ss += __shfl_xor(ss, 1, 16);
    s  += __shfl_xor(s, 2, 16);  ss += __shfl_xor(ss, 2, 16);
    s  += __shfl_xor(s, 4, 16);  ss += __shfl_xor(ss, 4, 16);
    s  += __shfl_xor(s, 8, 16);  ss += __shfl_xor(ss, 8, 16);
    float mean = s * (1.f/D_);
    float var  = ss * (1.f/D_) - mean*mean;
    float inv  = rsqrtf(var + EPS_);
    int grow = bm + row;
    float xs[5];
    float s2 = 0.f, ss2 = 0.f;
    #pragma unroll
    for (int c = 0; c < 5; ++c) {
      int col = j*5 + c;
      xs[c] = (v[c] - mean) * inv * low[col] + lob[col];
      x[(size_t)grow*D_ + col] = xs[c];
      s2 += xs[c]; ss2 += xs[c]*xs[c];
    }
    if (mode == 0) {
      s2  += __shfl_xor(s2, 1, 16);  ss2 += __shfl_xor(ss2, 1, 16);
      s2  += __shfl_xor(s2, 2, 16);  ss2 += __shfl_xor(ss2, 2, 16);
      s2  += __shfl_xor(s2, 4, 16);  ss2 += __shfl_xor(ss2, 4, 16);
      s2  += __shfl_xor(s2, 8, 16);  ss2 += __shfl_xor(ss2, 8, 16);
      float m2 = s2 * (1.f/D_);
      float v2 = ss2 * (1.f/D_) - m2*m2;
      float i2 = rsqrtf(v2 + EPS_);
      #pragma unroll
      for (int c = 0; c < 5; ++c) {
        int col = j*5 + c;
        hnsh[row][col] = f2bf((xs[c] - m2) * i2 * liw[col] + lib[col]);
      }
    } else {
      #pragma unroll
      for (int c = 0; c < 5; ++c)
        hnsh[row][j*5 + c] = f2bf(xs[c]);
    }
    hnsh[row][D_ + j] = 0;
  }

  if (mode == 0) {
    // ---- fused next-layer QKV -> qout/kvout (double-buffered; no race) ----
    __syncthreads();
    if (wv < 15) {
      int t = wv;
      f32x4 acc = {};
      #pragma unroll
      for (int kt = 0; kt < 3; ++kt) {
        bf16x8 a  = *(const bf16x8*)(&hnsh[r][kt*32 + g*8]);
        bf16x8 bb = *(const bf16x8*)(wqkvT_n + ((size_t)t*3 + kt)*512 + lane*8);
        acc = __builtin_amdgcn_mfma_f32_16x16x32_bf16(a, bb, acc, 0, 0, 0);
      }
      int col = t*16 + r;
      float bc = bqkv_n[col];
      #pragma unroll
      for (int rr = 0; rr < 4; ++rr) {
        int row = bm + g*4 + rr;
        float v = acc[rr] + bc;
        if (col < D_) qout[(size_t)row*D_ + col] = f2bf(v);
        else          kvout[(size_t)row*2*D_ + (col - D_)] = f2bf(v);
      }
    }
  } else {
    // ---- fused final projection: u-rows only ----
    int iu = bm % L_;
    if (iu >= RCT_) {
      __syncthreads();
      int bb2 = bm / L_;
      int urow0 = iu - RCT_;
      for (int t = wv; t < 48; t += 16) {
        f32x4 acc = {};
        #pragma unroll
        for (int kt = 0; kt < 3; ++kt) {
          bf16x8 a  = *(const bf16x8*)(&hnsh[r][kt*32 + g*8]);
          bf16x8 bb = *(const bf16x8*)(pwT + ((size_t)t*3 + kt)*512 + lane*8);
          acc = __builtin_amdgcn_mfma_f32_16x16x32_bf16(a, bb, acc, 0, 0, 0);
        }
        int col = t*16 + r;
        float bc = pb[col];
        #pragma unroll
        for (int rr = 0; rr < 4; ++rr) {
          int row = urow0 + g*4 + rr;
          out[((size_t)bb2*TU_ + row)*OUTD_ + col] = acc[rr] + bc;
        }
      }
    }
  }
}

extern "C" void kernel_launch(void* const* d_in, const int* in_sizes, int n_in,
                              void* d_out, int out_size, void* d_ws, size_t ws_size,
                              hipStream_t stream) {
  const float* mel     = (const float*)d_in[0];
  const int*   lengths = (const int*)  d_in[1];
  const float* ln_in_w = (const float*)d_in[2];
  const float* ln_in_b = (const float*)d_in[3];
  const float* wq      = (const float*)d_in[4];
  const float* bq      = (const float*)d_in[5];
  const float* wkv     = (const float*)d_in[6];
  const float* bkv     = (const float*)d_in[7];
  const float* wo      = (const float*)d_in[8];
  const float* bo      = (const float*)d_in[9];
  const float* ln_ff_w = (const float*)d_in[10];
  const float* ln_ff_b = (const float*)d_in[11];
  const float* w1      = (const float*)d_in[12];
  const float* b1      = (const float*)d_in[13];
  const float* w2      = (const float*)d_in[14];
  const float* b2      = (const float*)d_in[15];
  const float* ln_o_w  = (const float*)d_in[16];
  const float* ln_o_b  = (const float*)d_in[17];
  const float* pw      = (const float*)d_in[18];
  const float* pb      = (const float*)d_in[19];
  float* out = (float*)d_out;

  float* ws = (float*)d_ws;
  float* x     = ws; ws += NR_*D_;
  float* bqkv  = ws; ws += NLAYERS_*240;
  ushort_t* us = (ushort_t*)ws;
  ushort_t* qb0   = us; us += NR_*D_;
  ushort_t* kvb0  = us; us += NR_*2*D_;
  ushort_t* qb1   = us; us += NR_*D_;
  ushort_t* kvb1  = us; us += NR_*2*D_;
  ushort_t* wqkvT = us; us += S3_;
  ushort_t* woT   = us; us += S4_;
  ushort_t* pwT   = us; us += S5_;
  uchar_t* ub = (uchar_t*)us;
  uchar_t* w18 = ub; ub += S1_;
  uchar_t* w28 = ub; ub += S2_;

  k_wprep_all<<<WSM_BLK_ + W1_BLK_ + W2_BLK_, 256, 0, stream>>>(
      wq, wkv, wo, pw, bq, bkv, w1, w2, wqkvT, woT, pwT, bqkv, w18, w28,
      lengths, out);
  k_build_qkv<<<NR_/16, 512, 0, stream>>>(mel, ln_in_w, ln_in_b, wqkvT, bqkv,
                                          x, qb0, kvb0);

  for (int l = 0; l < NLAYERS_; ++l) {
    int last = (l == NLAYERS_-1);
    ushort_t* qi  = (l & 1) ? qb1  : qb0;
    ushort_t* kvi = (l & 1) ? kvb1 : kvb0;
    ushort_t* qo  = (l & 1) ? qb0  : qb1;
    ushort_t* kvo = (l & 1) ? kvb0 : kvb1;
    k_layer<<<NR_/16, 1024, 0, stream>>>(qi, kvi,
        woT + l*15*512, bo + l*D_,
        w18 + (size_t)l*FFN_*KP_, b1 + l*FFN_,
        w28 + (size_t)l*D_*FFN_, b2 + l*D_,
        ln_ff_w + l*D_, ln_ff_b + l*D_,
        ln_o_w + l*D_, ln_o_b + l*D_,
        ln_in_w + (last ? 0 : (l+1)*D_), ln_in_b + (last ? 0 : (l+1)*D_),
        last, x,
        wqkvT + (last ? 0 : (l+1)*45*512), bqkv + (last ? 0 : (l+1)*240),
        qo, kvo, pwT, pb, out);
  }
}